// Round 13
// baseline (12945.572 us; speedup 1.0000x reference)
//
#include <hip/hip_runtime.h>
#include <hip/hip_fp16.h>
#include <stdint.h>

// DagCellTorch R13: R12's pipelined MFMA recurrence + the missing vmcnt waits.
// Root cause of R12's NaN: inline-asm global_load has NO compiler-tracked vmcnt;
// every bank consume now does {s_waitcnt vmcnt(N); sched_barrier(0)} (rule #18).
// 32 blocks x 512 threads (8 waves), __launch_bounds__(512,2) -> 256 VGPR cap.
// Wave w owns col-tiles ct0=w, ct1=w+8. 18 phases/step; phase p computes from
// bank[p&1] while prefetching phase p+1 into bank[(p+1)&1] (asm, unsinkable).
// Barriers: lgkmcnt(0)+s_barrier only -> weight prefetches live across barriers.
// Math identical to R10 (passed, absmax 1.95e-3).

#define T_STEPS 128
#define B_ROWS  512
#define NH      256
#define BM      16
#define NBLK    (B_ROWS/BM)   // 32
#define NTHR    512

typedef _Float16 half8_t  __attribute__((ext_vector_type(8)));
typedef float    f32x4_t  __attribute__((ext_vector_type(4)));
typedef int      i32x4_t  __attribute__((ext_vector_type(4)));
union U4H8 { i32x4_t i; half8_t h; };
union I4F4 { i32x4_t i; float4 f; };

__device__ __forceinline__ float sigmoidf_(float x){
  float e = __expf(-fabsf(x));
  float s = 1.f/(1.f+e);
  return x>=0.f ? s : 1.f-s;
}
__device__ __forceinline__ float tanhf_(float x){
  float e = __expf(-2.f*fabsf(x));
  float r = (1.f-e)/(1.f+e);
  return x>=0.f ? r : -r;
}
__device__ __forceinline__ unsigned short f2h(float f){
  return __half_as_ushort(__float2half(f));   // RNE
}
__device__ __forceinline__ uint32_t packh(float a, float b){
  return (uint32_t)f2h(a) | ((uint32_t)f2h(b) << 16);
}
template<int ACT>  // 0 relu, 1 tanh, 2 sigmoid, 3 identity
__device__ __forceinline__ float actf(float v){
  if constexpr (ACT==0)      return fmaxf(v, 0.f);
  else if constexpr (ACT==1) return tanhf_(v);
  else if constexpr (ACT==2) return sigmoidf_(v);
  else                       return v;
}

// pinned-position global load; caller MUST s_waitcnt vmcnt before reading d
__device__ __forceinline__ i32x4_t pref_load(const void* p){
  i32x4_t d;
  asm volatile("global_load_dwordx4 %0, %1, off" : "=v"(d) : "v"(p));
  return d;
}
__device__ __forceinline__ f32x4_t mfma_(i32x4_t a, i32x4_t b, f32x4_t c){
  U4H8 ua, ub; ua.i = a; ub.i = b;
  return __builtin_amdgcn_mfma_f32_16x16x32_f16(ua.h, ub.h, c, 0, 0, 0);
}

// B-fragment weight pack (verified R10). dword idx =
// ((((p*2+mat)*16+ct)*8+ks)*64+lane)*4+dw ; col = ct*16+(lane&15),
// k = ks*32+(lane>>4)*8+dw*2 -> packh(W[col][k], W[col][k+1])
__global__ void prep_weights(const float* __restrict__ wxc, const float* __restrict__ wxh,
                             const float* __restrict__ whc, const float* __restrict__ whh,
                             const float* __restrict__ Wc,  const float* __restrict__ Wh,
                             uint32_t* __restrict__ WM){
  int idx = blockIdx.x*256 + threadIdx.x;
  if (idx >= 9*2*16*8*64*4) return;
  int dw   = idx & 3;
  int lane = (idx >> 2) & 63;
  int ks   = (idx >> 8) & 7;
  int ct   = (idx >> 11) & 15;
  int mat  = (idx >> 15) & 1;
  int p    = idx >> 16;
  int col  = ct*16 + (lane & 15);
  int k    = ks*32 + (lane >> 4)*8 + dw*2;
  const float* M;
  if (p == 0)      M = mat ? wxh : wxc;
  else if (p == 1) M = mat ? whh : whc;
  else             M = (mat ? Wh : Wc) + (size_t)(p-2)*NH*NH;
  WM[idx] = packh(M[(size_t)col*NH + k], M[(size_t)col*NH + k + 1]);
}

// C/D frag (row=4g+r, col=ct*16+n) -> A-frag LDS layout (verified R10).
__device__ __forceinline__ void write_hA(uint4 (* __restrict__ dst)[4][16],
                                         int ct, int lane, const float* hn)
{
  const int n = lane & 15, g = lane >> 4;
  float q0 = __shfl_xor(hn[0], 1);
  float q1 = __shfl_xor(hn[1], 1);
  float q2 = __shfl_xor(hn[2], 1);
  float q3 = __shfl_xor(hn[3], 1);
  if (!(lane & 1)){
    int ks  = ct >> 1;
    int g2  = ((ct & 1) << 1) | (n >> 3);
    int dwi = (n & 7) >> 1;
    ((uint32_t*)&dst[ks][g2][4*g + 0])[dwi] = packh(hn[0], q0);
    ((uint32_t*)&dst[ks][g2][4*g + 1])[dwi] = packh(hn[1], q1);
    ((uint32_t*)&dst[ks][g2][4*g + 2])[dwi] = packh(hn[2], q2);
    ((uint32_t*)&dst[ks][g2][4*g + 3])[dwi] = packh(hn[3], q3);
  }
}

// lgkm-only barrier (VMEM prefetches stay in flight), pinned
#define LBAR do { asm volatile("s_waitcnt lgkmcnt(0)" ::: "memory"); \
                  __builtin_amdgcn_s_barrier(); \
                  __builtin_amdgcn_sched_barrier(0); } while(0)
// counted VMEM waits + scheduler fence (rule #18)
#define VW16 do { asm volatile("s_waitcnt vmcnt(16)" ::: "memory"); \
                  __builtin_amdgcn_sched_barrier(0); } while(0)
#define VW18 do { asm volatile("s_waitcnt vmcnt(18)" ::: "memory"); \
                  __builtin_amdgcn_sched_barrier(0); } while(0)

#define PREF(BANK, IM) _Pragma("unroll") \
  for (int q_ = 0; q_ < 8; ++q_){ \
    BANK[q_]     = pref_load(wp0 + (IM)*8192 + q_*64); \
    BANK[q_ + 8] = pref_load(wp1 + (IM)*8192 + q_*64); }

#define CMP(BANK, A0, A1) _Pragma("unroll") \
  for (int q_ = 0; q_ < 8; ++q_){ \
    A0 = mfma_(afr[q_], BANK[q_],     A0); \
    A1 = mfma_(afr[q_], BANK[q_ + 8], A1); }

#define LOAD_AFR(BUF) _Pragma("unroll") \
  for (int q_ = 0; q_ < 8; ++q_) afr[q_] = *(const i32x4_t*)&hA[BUF][q_][g][n];

__global__ __launch_bounds__(NTHR, 2) void dag_mfma(
    const float* __restrict__ x,    // (T,B,NH) f32
    const float* __restrict__ h0,   // (B,NH) f32
    const float* __restrict__ bxc,  // (NH)
    const float* __restrict__ bxh,  // (NH)
    const uint32_t* __restrict__ WM,
    float* __restrict__ out)        // T*B*NH outputs then B*NH final hidden
{
  __shared__ uint4 hA[2][8][4][16];   // 16 KB fp16 h, A-frag layout, dbuf
  __shared__ uint4 xA[8][4][16];      // 8 KB fp16 x_t, A-frag layout
  __shared__ float redL[8][16];       // [wave][row] partial norm^2

  const int tid  = threadIdx.x;
  const int lane = tid & 63;
  const int w    = tid >> 6;         // wave 0..7
  const int n    = lane & 15;
  const int g    = lane >> 4;
  const int ct0  = w, ct1 = w + 8;
  const int r0   = blockIdx.x * BM;
  const i32x4_t* W4  = (const i32x4_t*)WM;
  const i32x4_t* wp0 = W4 + ct0*512 + lane;
  const i32x4_t* wp1 = W4 + ct1*512 + lane;

  // x-staging slots (constant per thread)
  const int d0 = tid*2,     d1 = tid*2 + 1;
  const int m20 = d0 >> 6,  kq0 = d0 & 63;
  const int m21 = d1 >> 6,  kq1 = d1 & 63;

  const float bc0 = bxc[ct0*16 + n], bc1 = bxc[ct1*16 + n];
  const float bh0 = bxh[ct0*16 + n], bh1 = bxh[ct1*16 + n];
  const f32x4_t zf = {0.f, 0.f, 0.f, 0.f};

  float hold0[4], hold1[4];
  #pragma unroll
  for (int r = 0; r < 4; ++r){
    hold0[r] = h0[(size_t)(r0 + 4*g + r)*NH + ct0*16 + n];
    hold1[r] = h0[(size_t)(r0 + 4*g + r)*NH + ct1*16 + n];
  }
  write_hA(hA[0], ct0, lane, hold0);
  write_hA(hA[0], ct1, lane, hold1);

  {  // xA for t=0 (compiler loads; consumed before asm prefetch below)
    float4 xv0 = ((const float4*)x)[((size_t)0*B_ROWS + r0 + m20)*64 + kq0];
    float4 xv1 = ((const float4*)x)[((size_t)0*B_ROWS + r0 + m21)*64 + kq1];
    int k00 = kq0*4, k01 = kq1*4;
    ((uint2*)&xA[k00>>5][(k00>>3)&3][m20])[(k00&7)>>2] =
        make_uint2(packh(xv0.x, xv0.y), packh(xv0.z, xv0.w));
    ((uint2*)&xA[k01>>5][(k01>>3)&3][m21])[(k01&7)>>2] =
        make_uint2(packh(xv1.x, xv1.y), packh(xv1.z, xv1.w));
  }

  // prologue: bank0 <- im0 weights (asm -> exactly 16 outstanding at loop entry)
  i32x4_t wb0[16], wb1[16];
  PREF(wb0, 0)
  i32x4_t afr[8];
  LBAR;

  #pragma unroll 1
  for (int t = 0; t < T_STEPS; ++t){
    f32x4_t aA0 = {bc0, bc0, bc0, bc0};
    f32x4_t aA1 = {bc1, bc1, bc1, bc1};
    f32x4_t aB0 = {bh0, bh0, bh0, bh0};
    f32x4_t aB1 = {bh1, bh1, bh1, bh1};

    // ===== node 0: phases im0 (X_A), im1 (X_B), im2 (H_A), im3 (H_B) =====
    #pragma unroll
    for (int q_ = 0; q_ < 8; ++q_) afr[q_] = *(const i32x4_t*)&xA[q_][g][n];
    PREF(wb1, 1)  VW16;  CMP(wb0, aA0, aA1)
    PREF(wb0, 2)  VW16;  CMP(wb1, aB0, aB1)
    LOAD_AFR(0)
    PREF(wb1, 3)  VW16;  CMP(wb0, aA0, aA1)
    PREF(wb0, 4)  VW16;  CMP(wb1, aB0, aB1)
    {
      float hn0[4], hn1[4];
      #pragma unroll
      for (int r = 0; r < 4; ++r){
        float c0 = sigmoidf_(aA0[r]); hn0[r] = c0*tanhf_(aB0[r]) + (1.f-c0)*hold0[r]; hold0[r] = hn0[r];
        float c1 = sigmoidf_(aA1[r]); hn1[r] = c1*tanhf_(aB1[r]) + (1.f-c1)*hold1[r]; hold1[r] = hn1[r];
      }
      write_hA(hA[1], ct0, lane, hn0);
      write_hA(hA[1], ct1, lane, hn1);
    }
    LBAR;

    // ===== edge 0 (relu), phases im4, im5; x(t+1) asm loads issued first =====
    {
      const bool doX = (t + 1 < T_STEPS);
      const int tn = doX ? (t + 1) : 0;   // always issue (uniform vmcnt counts)
      i32x4_t xr0 = pref_load(x + ((size_t)tn*B_ROWS + r0 + m20)*NH + kq0*4);
      i32x4_t xr1 = pref_load(x + ((size_t)tn*B_ROWS + r0 + m21)*NH + kq1*4);
      aA0 = zf; aA1 = zf; aB0 = zf; aB1 = zf;
      LOAD_AFR(1)
      PREF(wb1, 5)  VW18;  CMP(wb0, aA0, aA1)   // im4; {x2, im5} stay in flight
      PREF(wb0, 6)  VW16;  CMP(wb1, aB0, aB1)   // im5; completes x2 too
      float hn0[4], hn1[4];
      #pragma unroll
      for (int r = 0; r < 4; ++r){
        float c0 = sigmoidf_(aA0[r]); hn0[r] = c0*fmaxf(aB0[r],0.f) + (1.f-c0)*hold0[r]; hold0[r] = hn0[r];
        float c1 = sigmoidf_(aA1[r]); hn1[r] = c1*fmaxf(aB1[r],0.f) + (1.f-c1)*hold1[r]; hold1[r] = hn1[r];
      }
      write_hA(hA[0], ct0, lane, hn0);
      write_hA(hA[0], ct1, lane, hn1);
      if (doX){
        I4F4 u0, u1; u0.i = xr0; u1.i = xr1;
        int k00 = kq0*4, k01 = kq1*4;
        ((uint2*)&xA[k00>>5][(k00>>3)&3][m20])[(k00&7)>>2] =
            make_uint2(packh(u0.f.x, u0.f.y), packh(u0.f.z, u0.f.w));
        ((uint2*)&xA[k01>>5][(k01>>3)&3][m21])[(k01&7)>>2] =
            make_uint2(packh(u1.f.x, u1.f.y), packh(u1.f.z, u1.f.w));
      }
    }
    LBAR;

    // ===== edges 1..5: phases im(3+2K), im(4+2K); read hA[(K+1)&1], write hA[K&1]
    #define EDGE_ST(K, ACT_) { \
      aA0 = zf; aA1 = zf; aB0 = zf; aB1 = zf; \
      LOAD_AFR((K+1)&1) \
      PREF(wb1, 5+2*(K))  VW16;  CMP(wb0, aA0, aA1) \
      PREF(wb0, 6+2*(K))  VW16;  CMP(wb1, aB0, aB1) \
      float hn0[4], hn1[4]; \
      _Pragma("unroll") \
      for (int r = 0; r < 4; ++r){ \
        float c0 = sigmoidf_(aA0[r]); hn0[r] = c0*actf<ACT_>(aB0[r]) + (1.f-c0)*hold0[r]; hold0[r] = hn0[r]; \
        float c1 = sigmoidf_(aA1[r]); hn1[r] = c1*actf<ACT_>(aB1[r]) + (1.f-c1)*hold1[r]; hold1[r] = hn1[r]; \
      } \
      write_hA(hA[(K)&1], ct0, lane, hn0); \
      write_hA(hA[(K)&1], ct1, lane, hn1); \
      LBAR; }

    EDGE_ST(1, 1)   // tanh
    EDGE_ST(2, 2)   // sigmoid
    EDGE_ST(3, 3)   // identity
    EDGE_ST(4, 0)   // relu
    EDGE_ST(5, 1)   // tanh
    #undef EDGE_ST

    // ===== edge 6 (identity), phases im16, im17 (+ prefetch im0 of next step)
    {
      aA0 = zf; aA1 = zf; aB0 = zf; aB1 = zf;
      LOAD_AFR(1)
      PREF(wb1, 17)  VW16;  CMP(wb0, aA0, aA1)
      PREF(wb0, 0)   VW16;  CMP(wb1, aB0, aB1)
      float hn0[4], hn1[4];
      #pragma unroll
      for (int r = 0; r < 4; ++r){
        float c0 = sigmoidf_(aA0[r]); hn0[r] = c0*aB0[r] + (1.f-c0)*hold0[r];
        float c1 = sigmoidf_(aA1[r]); hn1[r] = c1*aB1[r] + (1.f-c1)*hold1[r];
      }
      #pragma unroll
      for (int r = 0; r < 4; ++r){
        float v = hn0[r]*hn0[r] + hn1[r]*hn1[r];
        v += __shfl_xor(v, 1); v += __shfl_xor(v, 2);
        v += __shfl_xor(v, 4); v += __shfl_xor(v, 8);
        if (n == 0) redL[w][4*g + r] = v;
      }
      LBAR;
      float tot = redL[0][n] + redL[1][n] + redL[2][n] + redL[3][n]
                + redL[4][n] + redL[5][n] + redL[6][n] + redL[7][n];
      float nrm  = sqrtf(tot);
      float srow = (nrm > 25.f) ? 25.f/nrm : 1.f;   // scale for row index n
      #pragma unroll
      for (int r = 0; r < 4; ++r){
        float sc = __shfl(srow, 4*g + r);
        hn0[r] *= sc; hn1[r] *= sc;
        hold0[r] = hn0[r]; hold1[r] = hn1[r];
        size_t ob = (size_t)t*(B_ROWS*NH) + (size_t)(r0 + 4*g + r)*NH;
        out[ob + ct0*16 + n] = hn0[r];
        out[ob + ct1*16 + n] = hn1[r];
      }
      write_hA(hA[0], ct0, lane, hn0);
      write_hA(hA[0], ct1, lane, hn1);
    }
    LBAR;
  }

  #pragma unroll
  for (int r = 0; r < 4; ++r){
    size_t ob = (size_t)T_STEPS*(B_ROWS*NH) + (size_t)(r0 + 4*g + r)*NH;
    out[ob + ct0*16 + n] = hold0[r];
    out[ob + ct1*16 + n] = hold1[r];
  }
}

extern "C" void kernel_launch(void* const* d_in, const int* in_sizes, int n_in,
                              void* d_out, int out_size, void* d_ws, size_t ws_size,
                              hipStream_t stream) {
  const float* x   = (const float*)d_in[0];
  const float* h0  = (const float*)d_in[1];
  const float* wxc = (const float*)d_in[2];
  const float* bxc = (const float*)d_in[3];
  const float* wxh = (const float*)d_in[4];
  const float* bxh = (const float*)d_in[5];
  const float* whc = (const float*)d_in[6];
  const float* whh = (const float*)d_in[7];
  const float* Wc  = (const float*)d_in[8];
  const float* Wh  = (const float*)d_in[9];
  uint32_t* WM = (uint32_t*)d_ws;   // 589824 dwords = 2.36 MB

  const int total = 9*2*16*8*64*4;
  prep_weights<<<(total + 255)/256, 256, 0, stream>>>(wxc, wxh, whc, whh, Wc, Wh, WM);
  dag_mfma<<<NBLK, NTHR, 0, stream>>>(x, h0, bxc, bxh, WM, (float*)d_out);
}